// Round 18
// baseline (320.964 us; speedup 1.0000x reference)
//
#include <hip/hip_runtime.h>

// x[T=4,B=32,N=1024,C=256] -> Linear -> BN -> LIF -> Linear -> BN -> LIF
// M = 131072 rows, fp32 in/out.
// Round 18 = r17 + K-chunk double-buffer (2 chunks of K=128): chunk1 loads issued
// before chunk0 compute -> half the stage burst overlaps MFMA. Same tile/occupancy.

typedef __attribute__((ext_vector_type(8))) short bf16x8;
typedef __attribute__((ext_vector_type(8))) _Float16 f16x8;
typedef __attribute__((ext_vector_type(4))) _Float16 f16x4;
typedef __attribute__((ext_vector_type(4))) float f32x4;

__device__ __forceinline__ unsigned short f32_to_bf16_rne(float f) {
    unsigned int u = __builtin_bit_cast(unsigned int, f);
    u += 0x7FFFu + ((u >> 16) & 1u);
    return (unsigned short)(u >> 16);
}
__device__ __forceinline__ float bf16_to_f32(unsigned short h) {
    unsigned int u = ((unsigned int)h) << 16;
    return __builtin_bit_cast(float, u);
}
__device__ __forceinline__ int xcd_swz(int bid, int nwg) {
    int per = nwg >> 3;
    return (bid & 7) * per + (bid >> 3);
}

__global__ __launch_bounds__(256) void split_w1(const float* __restrict__ W1,
                                                _Float16* __restrict__ BhiT,
                                                _Float16* __restrict__ BloT) {
    int i = blockIdx.x * 256 + threadIdx.x;
    int k = i >> 8, n = i & 255;
    float w = W1[i];
    _Float16 hi = (_Float16)w;
    _Float16 lo = (_Float16)((w - (float)hi) * 4096.0f);
    BhiT[(size_t)n * 256 + k] = hi;
    BloT[(size_t)n * 256 + k] = lo;
}

__global__ __launch_bounds__(256) void split_w2(const float* __restrict__ W2,
                                                unsigned short* __restrict__ Bt) {
    int i = blockIdx.x * 256 + threadIdx.x;
    int k = i >> 8, n = i & 255;
    float w = W2[i];
    unsigned short hi = f32_to_bf16_rne(w);
    float r = w - bf16_to_f32(hi);
    unsigned short mid = f32_to_bf16_rne(r);
    float r2 = r - bf16_to_f32(mid);
    unsigned short lo = f32_to_bf16_rne(r2);
    Bt[(size_t)(0 * 256 + n) * 256 + k] = hi;
    Bt[(size_t)(1 * 256 + n) * 256 + k] = mid;
    Bt[(size_t)(2 * 256 + n) * 256 + k] = lo;
}

// ---------------- GEMM1: BM=64, 8 waves x 32 cols, K-chunk dbuf (2 x K=128) ----------
__global__ __launch_bounds__(512, 4) void gemm1_mfma(const float* __restrict__ A,
                                                     const _Float16* __restrict__ Bhi,
                                                     const _Float16* __restrict__ Blo,
                                                     const float* __restrict__ bias,
                                                     float* __restrict__ C,
                                                     double* __restrict__ partial) {
    __shared__ __align__(16) _Float16 AhiS[2][64 * 128];  // 2 x 16 KB
    __shared__ __align__(16) _Float16 AloS[2][64 * 128];  // 2 x 16 KB
    const int blk = xcd_swz(blockIdx.x, gridDim.x);
    const size_t m0 = (size_t)blk * 64;
    const int tid = threadIdx.x;
    const int lane = tid & 63;
    const int wave = tid >> 6;   // 0..7, owns cols 32*wave .. 32*wave+31
    const int lrow = lane & 15, lchunk = lane >> 4;

    const _Float16* BhiB = Bhi + ((size_t)(32 * wave + lrow)) * 256 + lchunk * 8;
    const _Float16* BloB = Blo + ((size_t)(32 * wave + lrow)) * 256 + lchunk * 8;

    float4 ra[4], rb[4];
#define ISSUE1(R, ck)                                                         \
    {                                                                         \
        const float* s_ = A + m0 * 256 + (ck) * 128;                          \
        _Pragma("unroll") for (int j = 0; j < 4; ++j) {                       \
            unsigned i4 = (unsigned)(j * 512 + tid);                          \
            R[j] = *(const float4*)(s_ + (size_t)(i4 >> 5) * 256 + (i4 & 31) * 4); \
        }                                                                     \
    }
#define CW1(R, buf)                                                           \
    _Pragma("unroll") for (int j = 0; j < 4; ++j) {                           \
        unsigned i4 = (unsigned)(j * 512 + tid);                              \
        unsigned row = i4 >> 5, colq = i4 & 31;                               \
        float f0 = R[j].x, f1 = R[j].y, f2 = R[j].z, f3 = R[j].w;             \
        f16x4 hi4, lo4;                                                       \
        _Float16 h0 = (_Float16)f0; hi4[0] = h0; lo4[0] = (_Float16)((f0 - (float)h0) * 4096.0f); \
        _Float16 h1 = (_Float16)f1; hi4[1] = h1; lo4[1] = (_Float16)((f1 - (float)h1) * 4096.0f); \
        _Float16 h2 = (_Float16)f2; hi4[2] = h2; lo4[2] = (_Float16)((f2 - (float)h2) * 4096.0f); \
        _Float16 h3 = (_Float16)f3; hi4[3] = h3; lo4[3] = (_Float16)((f3 - (float)h3) * 4096.0f); \
        unsigned off = (row * 256u + colq * 8u) ^ ((row & 7u) << 4);          \
        *(f16x4*)((char*)AhiS[buf] + off) = hi4;                              \
        *(f16x4*)((char*)AloS[buf] + off) = lo4;                              \
    }

    ISSUE1(ra, 0)
    CW1(ra, 0)
    ISSUE1(rb, 1)
    __syncthreads();

    f32x4 acc0[4][2] = {}, acc1[4][2] = {};

#define COMPUTE1(buf, K0)                                                     \
    _Pragma("unroll") for (int kl = 0; kl < 4; ++kl) {                        \
        const int k0 = (K0) + kl;                                             \
        f16x8 bh[2], bl[2];                                                   \
        _Pragma("unroll") for (int nf = 0; nf < 2; ++nf) {                    \
            bh[nf] = *(const f16x8*)(BhiB + nf * 4096 + k0 * 32);             \
            bl[nf] = *(const f16x8*)(BloB + nf * 4096 + k0 * 32);             \
        }                                                                     \
        _Pragma("unroll") for (int half = 0; half < 2; ++half) {              \
            f16x8 ah[2], al[2];                                               \
            _Pragma("unroll") for (int m = 0; m < 2; ++m) {                   \
                unsigned r = (unsigned)(32 * half + 16 * m + lrow);           \
                unsigned off = (r * 256u + (unsigned)(kl * 64 + lchunk * 16)) ^ ((r & 7u) << 4); \
                ah[m] = *(const f16x8*)((const char*)AhiS[buf] + off);        \
                al[m] = *(const f16x8*)((const char*)AloS[buf] + off);        \
            }                                                                 \
            __builtin_amdgcn_s_setprio(1);                                    \
            _Pragma("unroll") for (int nf = 0; nf < 2; ++nf)                  \
            _Pragma("unroll") for (int m = 0; m < 2; ++m) {                   \
                const int mf = half * 2 + m;                                  \
                acc0[mf][nf] = __builtin_amdgcn_mfma_f32_16x16x32_f16(        \
                    ah[m], bh[nf], acc0[mf][nf], 0, 0, 0);                    \
                acc1[mf][nf] = __builtin_amdgcn_mfma_f32_16x16x32_f16(        \
                    ah[m], bl[nf], acc1[mf][nf], 0, 0, 0);                    \
                acc1[mf][nf] = __builtin_amdgcn_mfma_f32_16x16x32_f16(        \
                    al[m], bh[nf], acc1[mf][nf], 0, 0, 0);                    \
            }                                                                 \
            __builtin_amdgcn_s_setprio(0);                                    \
        }                                                                     \
    }

    COMPUTE1(0, 0)
    CW1(rb, 1)
    __syncthreads();
    COMPUTE1(1, 4)
#undef ISSUE1
#undef CW1
#undef COMPUTE1

    const float UNSCALE = 1.0f / 4096.0f;
#pragma unroll
    for (int nf = 0; nf < 2; ++nf) {
        int col = 32 * wave + 16 * nf + lrow;
        float bvv = bias[col];
        double ss = 0.0, qq = 0.0;
#pragma unroll
        for (int mf = 0; mf < 4; ++mf) {
            size_t rowb = m0 + 16 * mf + 4 * lchunk;
#pragma unroll
            for (int e = 0; e < 4; ++e) {
                float hv = acc0[mf][nf][e] + acc1[mf][nf][e] * UNSCALE + bvv;
                C[(rowb + e) * 256 + col] = hv;
                ss += (double)hv;
                qq += (double)hv * (double)hv;
            }
        }
        ss += __shfl_xor(ss, 16);
        ss += __shfl_xor(ss, 32);
        qq += __shfl_xor(qq, 16);
        qq += __shfl_xor(qq, 32);
        if (lane < 16) {
            partial[(size_t)blk * 512 + col] = ss;
            partial[(size_t)blk * 512 + 256 + col] = qq;
        }
    }
}

// ------- GEMM2 fused: BN+LIF staging, K-chunk dbuf (2 x 128 channels) ----------------
__global__ __launch_bounds__(512, 4) void gemm2_fused(const float* __restrict__ h,
                                                      const float2* __restrict__ ss1,
                                                      const unsigned short* __restrict__ Bt,
                                                      const float* __restrict__ bias,
                                                      float* __restrict__ C,
                                                      double* __restrict__ partial,
                                                      int bnRows) {
    __shared__ __align__(16) unsigned short AswS[2][64 * 128];  // 2 x 16 KB
    const int blk = xcd_swz(blockIdx.x, gridDim.x);
    const int bn0 = blk * 16;
    const int tid = threadIdx.x;
    const int lane = tid & 63;
    const int wave = tid >> 6;
    const int lrow = lane & 15, lchunk = lane >> 4;

    const unsigned short* Bbase =
        Bt + ((size_t)(32 * wave + lrow)) * 256 + lchunk * 8;

    // slot: bn = tid>>5 (0..15), colq = tid&31 (0..31); chunk ck covers ch 128*ck..+127
    const int sbn = tid >> 5, scq = tid & 31;
    float4 ra[4], rb[4];
#define ISSUE2(R, ck)                                                         \
    {                                                                         \
        size_t rb_ = (size_t)(bn0 + sbn) * 256 + (ck) * 128 + scq * 4;        \
        _Pragma("unroll") for (int t4 = 0; t4 < 4; ++t4)                      \
            R[t4] = *(const float4*)(h + (size_t)t4 * bnRows * 256 + rb_);    \
    }
#define CW2(R, buf, ck)                                                       \
    {                                                                         \
        int c0 = (ck) * 128 + scq * 4;                                        \
        float2 p0 = ss1[c0], p1 = ss1[c0 + 1], p2 = ss1[c0 + 2], p3 = ss1[c0 + 3]; \
        float4 v = make_float4(0.f, 0.f, 0.f, 0.f);                           \
        _Pragma("unroll") for (int t4 = 0; t4 < 4; ++t4) {                    \
            float4 hv = R[t4];                                                \
            float x0 = hv.x * p0.x + p0.y;                                    \
            float x1 = hv.y * p1.x + p1.y;                                    \
            float x2 = hv.z * p2.x + p2.y;                                    \
            float x3 = hv.w * p3.x + p3.y;                                    \
            v.x = (v.x + x0) * 0.5f;                                          \
            v.y = (v.y + x1) * 0.5f;                                          \
            v.z = (v.z + x2) * 0.5f;                                          \
            v.w = (v.w + x3) * 0.5f;                                          \
            ushort4 sp;                                                       \
            sp.x = (v.x >= 1.0f) ? 0x3F80 : 0;                                \
            sp.y = (v.y >= 1.0f) ? 0x3F80 : 0;                                \
            sp.z = (v.z >= 1.0f) ? 0x3F80 : 0;                                \
            sp.w = (v.w >= 1.0f) ? 0x3F80 : 0;                                \
            v.x = (v.x >= 1.0f) ? 0.0f : v.x;                                 \
            v.y = (v.y >= 1.0f) ? 0.0f : v.y;                                 \
            v.z = (v.z >= 1.0f) ? 0.0f : v.z;                                 \
            v.w = (v.w >= 1.0f) ? 0.0f : v.w;                                 \
            unsigned row = (unsigned)(t4 * 16 + sbn);                         \
            unsigned off = (row * 256u + (unsigned)scq * 8u) ^ ((row & 7u) << 4); \
            *(ushort4*)((char*)AswS[buf] + off) = sp;                         \
        }                                                                     \
    }

    ISSUE2(ra, 0)
    CW2(ra, 0, 0)
    ISSUE2(rb, 1)
    __syncthreads();

    f32x4 acc[4][2] = {};

#define COMPUTE2(buf, K0)                                                     \
    _Pragma("unroll") for (int kl = 0; kl < 4; ++kl) {                        \
        const int k0 = (K0) + kl;                                             \
        bf16x8 bb[6];                                                         \
        _Pragma("unroll") for (int t_ = 0; t_ < 3; ++t_)                      \
        _Pragma("unroll") for (int nf = 0; nf < 2; ++nf)                      \
            bb[t_ * 2 + nf] = *(const bf16x8*)(Bbase + (size_t)t_ * 65536 +   \
                                               nf * 4096 + k0 * 32);          \
        _Pragma("unroll") for (int half = 0; half < 2; ++half) {              \
            bf16x8 af[2];                                                     \
            _Pragma("unroll") for (int m = 0; m < 2; ++m) {                   \
                unsigned r = (unsigned)(32 * half + 16 * m + lrow);           \
                unsigned off = (r * 256u + (unsigned)(kl * 64 + lchunk * 16)) ^ ((r & 7u) << 4); \
                af[m] = *(const bf16x8*)((const char*)AswS[buf] + off);       \
            }                                                                 \
            __builtin_amdgcn_s_setprio(1);                                    \
            _Pragma("unroll") for (int t_ = 0; t_ < 3; ++t_)                  \
            _Pragma("unroll") for (int nf = 0; nf < 2; ++nf)                  \
            _Pragma("unroll") for (int m = 0; m < 2; ++m) {                   \
                const int mf = half * 2 + m;                                  \
                acc[mf][nf] = __builtin_amdgcn_mfma_f32_16x16x32_bf16(        \
                    af[m], bb[t_ * 2 + nf], acc[mf][nf], 0, 0, 0);            \
            }                                                                 \
            __builtin_amdgcn_s_setprio(0);                                    \
        }                                                                     \
    }

    COMPUTE2(0, 0)
    CW2(rb, 1, 1)
    __syncthreads();
    COMPUTE2(1, 4)
#undef ISSUE2
#undef CW2
#undef COMPUTE2

#pragma unroll
    for (int nf = 0; nf < 2; ++nf) {
        int col = 32 * wave + 16 * nf + lrow;
        float bvv = bias[col];
        double ss = 0.0, qq = 0.0;
#pragma unroll
        for (int mf = 0; mf < 4; ++mf) {
            int Lbase = 16 * mf + 4 * lchunk;
#pragma unroll
            for (int e = 0; e < 4; ++e) {
                int L = Lbase + e;
                size_t G = (size_t)(L >> 4) * bnRows + bn0 + (L & 15);
                float hv = acc[mf][nf][e] + bvv;
                C[G * 256 + col] = hv;
                ss += (double)hv;
                qq += (double)hv * (double)hv;
            }
        }
        ss += __shfl_xor(ss, 16);
        ss += __shfl_xor(ss, 32);
        qq += __shfl_xor(qq, 16);
        qq += __shfl_xor(qq, 32);
        if (lane < 16) {
            partial[(size_t)blk * 512 + col] = ss;
            partial[(size_t)blk * 512 + 256 + col] = qq;
        }
    }
}

__global__ __launch_bounds__(256) void finalize_stats(const double* __restrict__ partial,
                                                      const float* __restrict__ gamma,
                                                      const float* __restrict__ beta,
                                                      float2* __restrict__ ss,
                                                      int nblocks, double invM) {
    const int c = blockIdx.x;
    const int t = threadIdx.x;
    __shared__ double sh[256];
    __shared__ double sh2[256];
    double s = 0.0, s2 = 0.0;
    for (int b = t; b < nblocks; b += 256) {
        s += partial[(size_t)b * 512 + c];
        s2 += partial[(size_t)b * 512 + 256 + c];
    }
    sh[t] = s;
    sh2[t] = s2;
    __syncthreads();
#pragma unroll
    for (int off = 128; off > 0; off >>= 1) {
        if (t < off) {
            sh[t] += sh[t + off];
            sh2[t] += sh2[t + off];
        }
        __syncthreads();
    }
    if (t == 0) {
        double mu = sh[0] * invM;
        double var = sh2[0] * invM - mu * mu;
        double rstd = 1.0 / sqrt(var + 1e-5);
        double sc = (double)gamma[c] * rstd;
        ss[c] = make_float2((float)sc, (float)((double)beta[c] - mu * sc));
    }
}

__global__ __launch_bounds__(256) void bnlif_f32(const float* __restrict__ h,
                                                 const float2* __restrict__ ss,
                                                 float* __restrict__ out,
                                                 int slab4) {
    int t4 = blockIdx.x * 256 + threadIdx.x;
    if (t4 >= slab4) return;
    size_t idx = (size_t)t4 * 4;
    int c0 = (int)(idx & 255);
    float2 p0 = ss[c0], p1 = ss[c0 + 1], p2 = ss[c0 + 2], p3 = ss[c0 + 3];
    size_t slab = (size_t)slab4 * 4;
    float4 v = make_float4(0.f, 0.f, 0.f, 0.f);
#pragma unroll
    for (int t = 0; t < 4; ++t) {
        float4 hv = *(const float4*)(h + (size_t)t * slab + idx);
        float x0 = hv.x * p0.x + p0.y;
        float x1 = hv.y * p1.x + p1.y;
        float x2 = hv.z * p2.x + p2.y;
        float x3 = hv.w * p3.x + p3.y;
        v.x = (v.x + x0) * 0.5f;
        v.y = (v.y + x1) * 0.5f;
        v.z = (v.z + x2) * 0.5f;
        v.w = (v.w + x3) * 0.5f;
        float4 sp;
        sp.x = (v.x >= 1.0f) ? 1.0f : 0.0f;
        sp.y = (v.y >= 1.0f) ? 1.0f : 0.0f;
        sp.z = (v.z >= 1.0f) ? 1.0f : 0.0f;
        sp.w = (v.w >= 1.0f) ? 1.0f : 0.0f;
        v.x = (v.x >= 1.0f) ? 0.0f : v.x;
        v.y = (v.y >= 1.0f) ? 0.0f : v.y;
        v.z = (v.z >= 1.0f) ? 0.0f : v.z;
        v.w = (v.w >= 1.0f) ? 0.0f : v.w;
        *(float4*)(out + (size_t)t * slab + idx) = sp;
    }
}

extern "C" void kernel_launch(void* const* d_in, const int* in_sizes, int n_in,
                              void* d_out, int out_size, void* d_ws, size_t ws_size,
                              hipStream_t stream) {
    const float* x  = (const float*)d_in[0];
    const float* W1 = (const float*)d_in[1];
    const float* b1 = (const float*)d_in[2];
    const float* g1 = (const float*)d_in[3];
    const float* be1 = (const float*)d_in[4];
    const float* W2 = (const float*)d_in[5];
    const float* b2 = (const float*)d_in[6];
    const float* g2 = (const float*)d_in[7];
    const float* be2 = (const float*)d_in[8];
    float* out = (float*)d_out;

    const int M = in_sizes[0] / 256;            // 131072
    const int bnRows = M / 4;                   // 32768
    const size_t hBytes = (size_t)M * 256 * 4;  // 128 MiB

    char* ws = (char*)d_ws;
    float* h = (float*)ws;
    double* partial = (double*)(ws + hBytes);                // 8 MiB
    unsigned short* W2catT = (unsigned short*)(ws + hBytes + (size_t)2048 * 512 * 8);
    float2* ss1 = (float2*)((char*)W2catT + 3 * 256 * 256 * 2);
    float2* ss2 = ss1 + 256;
    _Float16* W1hiT = (_Float16*)(ss2 + 256);
    _Float16* W1loT = W1hiT + 256 * 256;

    const int slab4 = M * 16;
    const double invM = 1.0 / (double)M;
    const int NB1 = M / 64;        // 2048
    const int NB2 = bnRows / 16;   // 2048

    dim3 blk(256);

    split_w1<<<dim3(256), blk, 0, stream>>>(W1, W1hiT, W1loT);
    split_w2<<<dim3(256), blk, 0, stream>>>(W2, W2catT);

    gemm1_mfma<<<dim3(NB1), dim3(512), 0, stream>>>(x, W1hiT, W1loT, b1, h, partial);
    finalize_stats<<<dim3(256), blk, 0, stream>>>(partial, g1, be1, ss1, NB1, invM);

    gemm2_fused<<<dim3(NB2), dim3(512), 0, stream>>>(h, ss1, W2catT, b2, h, partial, bnRows);
    finalize_stats<<<dim3(256), blk, 0, stream>>>(partial, g2, be2, ss2, NB2, invM);
    bnlif_f32<<<dim3(slab4 / 256), blk, 0, stream>>>(h, ss2, out, slab4);
}

// Round 19
// 290.569 us; speedup vs baseline: 1.1046x; 1.1046x over previous
//
#include <hip/hip_runtime.h>

// x[T=4,B=32,N=1024,C=256] -> Linear -> BN -> LIF -> Linear -> BN -> LIF
// M = 131072 rows, fp32 in/out.
// Round 19 = exact revert to round 17 (best, 290.8us). Wave tile 64x32 (acc 64
// AGPR), B single-buffered, 16 waves/CU, XCD swizzle, setprio, fused stats/LIF.

typedef __attribute__((ext_vector_type(8))) short bf16x8;
typedef __attribute__((ext_vector_type(8))) _Float16 f16x8;
typedef __attribute__((ext_vector_type(4))) _Float16 f16x4;
typedef __attribute__((ext_vector_type(4))) float f32x4;

__device__ __forceinline__ unsigned short f32_to_bf16_rne(float f) {
    unsigned int u = __builtin_bit_cast(unsigned int, f);
    u += 0x7FFFu + ((u >> 16) & 1u);
    return (unsigned short)(u >> 16);
}
__device__ __forceinline__ float bf16_to_f32(unsigned short h) {
    unsigned int u = ((unsigned int)h) << 16;
    return __builtin_bit_cast(float, u);
}
// bijective XCD swizzle (requires nwg % 8 == 0)
__device__ __forceinline__ int xcd_swz(int bid, int nwg) {
    int per = nwg >> 3;
    return (bid & 7) * per + (bid >> 3);
}

__global__ __launch_bounds__(256) void split_w1(const float* __restrict__ W1,
                                                _Float16* __restrict__ BhiT,
                                                _Float16* __restrict__ BloT) {
    int i = blockIdx.x * 256 + threadIdx.x;
    int k = i >> 8, n = i & 255;
    float w = W1[i];
    _Float16 hi = (_Float16)w;
    _Float16 lo = (_Float16)((w - (float)hi) * 4096.0f);
    BhiT[(size_t)n * 256 + k] = hi;
    BloT[(size_t)n * 256 + k] = lo;
}

__global__ __launch_bounds__(256) void split_w2(const float* __restrict__ W2,
                                                unsigned short* __restrict__ Bt) {
    int i = blockIdx.x * 256 + threadIdx.x;
    int k = i >> 8, n = i & 255;
    float w = W2[i];
    unsigned short hi = f32_to_bf16_rne(w);
    float r = w - bf16_to_f32(hi);
    unsigned short mid = f32_to_bf16_rne(r);
    float r2 = r - bf16_to_f32(mid);
    unsigned short lo = f32_to_bf16_rne(r2);
    Bt[(size_t)(0 * 256 + n) * 256 + k] = hi;
    Bt[(size_t)(1 * 256 + n) * 256 + k] = mid;
    Bt[(size_t)(2 * 256 + n) * 256 + k] = lo;
}

// ---------------- GEMM1 (MFMA, fp16 2-split x 3 products), BM=64, 8 waves x 32 cols --
__global__ __launch_bounds__(512, 4) void gemm1_mfma(const float* __restrict__ A,
                                                     const _Float16* __restrict__ Bhi,
                                                     const _Float16* __restrict__ Blo,
                                                     const float* __restrict__ bias,
                                                     float* __restrict__ C,
                                                     double* __restrict__ partial) {
    __shared__ __align__(16) _Float16 Ahi[64 * 256];  // 32 KB
    __shared__ __align__(16) _Float16 Alo[64 * 256];  // 32 KB
    const int blk = xcd_swz(blockIdx.x, gridDim.x);
    const size_t m0 = (size_t)blk * 64;
    const int tid = threadIdx.x;
    const int lane = tid & 63;
    const int wave = tid >> 6;   // 0..7, owns cols 32*wave .. 32*wave+31
    const int lrow = lane & 15, lchunk = lane >> 4;

    const _Float16* BhiB = Bhi + ((size_t)(32 * wave + lrow)) * 256 + lchunk * 8;
    const _Float16* BloB = Blo + ((size_t)(32 * wave + lrow)) * 256 + lchunk * 8;

    // ---- stage A tile: 64x256 fp32 -> (hi, lo*4096) fp16 LDS, swizzled ----
    {
        const float* src = A + m0 * 256;
        float4 rr[8];
#pragma unroll
        for (int it = 0; it < 8; ++it)
            rr[it] = *(const float4*)(src + (size_t)(it * 512 + tid) * 4);
#pragma unroll
        for (int it = 0; it < 8; ++it) {
            unsigned i4 = (unsigned)(it * 512 + tid);
            float f[4] = {rr[it].x, rr[it].y, rr[it].z, rr[it].w};
            f16x4 hi4, lo4;
#pragma unroll
            for (int e = 0; e < 4; ++e) {
                _Float16 hh = (_Float16)f[e];
                hi4[e] = hh;
                lo4[e] = (_Float16)((f[e] - (float)hh) * 4096.0f);
            }
            unsigned off = i4 * 8u;                     // row = off>>9 (512B rows)
            unsigned swz = off ^ (((off >> 9) & 7u) << 4);
            *(f16x4*)((char*)Ahi + swz) = hi4;
            *(f16x4*)((char*)Alo + swz) = lo4;
        }
    }
    __syncthreads();

    f32x4 acc0[4][2] = {}, acc1[4][2] = {};

#pragma unroll
    for (int k0 = 0; k0 < 8; ++k0) {
        f16x8 bh[2], bl[2];
#pragma unroll
        for (int nf = 0; nf < 2; ++nf) {
            bh[nf] = *(const f16x8*)(BhiB + nf * 4096 + k0 * 32);
            bl[nf] = *(const f16x8*)(BloB + nf * 4096 + k0 * 32);
        }
#pragma unroll
        for (int half = 0; half < 2; ++half) {
            f16x8 ah[2], al[2];
#pragma unroll
            for (int m = 0; m < 2; ++m) {
                unsigned r = (unsigned)(32 * half + 16 * m + lrow);
                unsigned off = (r * 512u + (unsigned)(k0 * 64 + lchunk * 16)) ^ ((r & 7u) << 4);
                ah[m] = *(const f16x8*)((const char*)Ahi + off);
                al[m] = *(const f16x8*)((const char*)Alo + off);
            }
            __builtin_amdgcn_s_setprio(1);
#pragma unroll
            for (int nf = 0; nf < 2; ++nf)
#pragma unroll
                for (int m = 0; m < 2; ++m) {
                    const int mf = half * 2 + m;
                    acc0[mf][nf] = __builtin_amdgcn_mfma_f32_16x16x32_f16(
                        ah[m], bh[nf], acc0[mf][nf], 0, 0, 0);
                    acc1[mf][nf] = __builtin_amdgcn_mfma_f32_16x16x32_f16(
                        ah[m], bl[nf], acc1[mf][nf], 0, 0, 0);
                    acc1[mf][nf] = __builtin_amdgcn_mfma_f32_16x16x32_f16(
                        al[m], bh[nf], acc1[mf][nf], 0, 0, 0);
                }
            __builtin_amdgcn_s_setprio(0);
        }
    }

    // ---- C write (h = acc0 + acc1*2^-12 + bias) + per-wave column stats -------------
    const float UNSCALE = 1.0f / 4096.0f;
#pragma unroll
    for (int nf = 0; nf < 2; ++nf) {
        int col = 32 * wave + 16 * nf + lrow;
        float bvv = bias[col];
        double ss = 0.0, qq = 0.0;
#pragma unroll
        for (int mf = 0; mf < 4; ++mf) {
            size_t rowb = m0 + 16 * mf + 4 * lchunk;
#pragma unroll
            for (int e = 0; e < 4; ++e) {
                float hv = acc0[mf][nf][e] + acc1[mf][nf][e] * UNSCALE + bvv;
                C[(rowb + e) * 256 + col] = hv;
                ss += (double)hv;
                qq += (double)hv * (double)hv;
            }
        }
        ss += __shfl_xor(ss, 16);
        ss += __shfl_xor(ss, 32);
        qq += __shfl_xor(qq, 16);
        qq += __shfl_xor(qq, 32);
        if (lane < 16) {
            partial[(size_t)blk * 512 + col] = ss;
            partial[(size_t)blk * 512 + 256 + col] = qq;
        }
    }
}

// ------- GEMM2 fused: BN+LIF in staging (16 bn x 4 t), spikes @ W2 (bf16x3) ----------
__global__ __launch_bounds__(512, 4) void gemm2_fused(const float* __restrict__ h,
                                                      const float2* __restrict__ ss1,
                                                      const unsigned short* __restrict__ Bt,
                                                      const float* __restrict__ bias,
                                                      float* __restrict__ C,
                                                      double* __restrict__ partial,
                                                      int bnRows) {
    __shared__ __align__(16) unsigned short Asw[64 * 256];  // 32 KB bf16 spikes
    const int blk = xcd_swz(blockIdx.x, gridDim.x);
    const int bn0 = blk * 16;
    const int tid = threadIdx.x;
    const int lane = tid & 63;
    const int wave = tid >> 6;   // 0..7, owns cols 32*wave .. 32*wave+31
    const int lrow = lane & 15, lchunk = lane >> 4;

    const unsigned short* Bbase =
        Bt + ((size_t)(32 * wave + lrow)) * 256 + lchunk * 8;

    // ---- stage: ISSUE h-loads, then BN+LIF convert -> bf16 spikes in swizzled LDS ---
    {
        float4 rr[8];
#pragma unroll
        for (int it = 0; it < 2; ++it) {
            int slot = it * 512 + tid;        // 1024 slots: bn(16) x colq(64)
            int bn = slot >> 6;
            int colq = slot & 63;
            size_t rb = (size_t)(bn0 + bn) * 256 + colq * 4;
#pragma unroll
            for (int t4 = 0; t4 < 4; ++t4)
                rr[it * 4 + t4] = *(const float4*)(h + (size_t)t4 * bnRows * 256 + rb);
        }
#pragma unroll
        for (int it = 0; it < 2; ++it) {
            int slot = it * 512 + tid;
            int bn = slot >> 6;
            int colq = slot & 63;
            int c0 = colq * 4;
            float2 p0 = ss1[c0], p1 = ss1[c0 + 1], p2 = ss1[c0 + 2], p3 = ss1[c0 + 3];
            float4 v = make_float4(0.f, 0.f, 0.f, 0.f);
#pragma unroll
            for (int t4 = 0; t4 < 4; ++t4) {
                float4 hv = rr[it * 4 + t4];
                float x0 = hv.x * p0.x + p0.y;
                float x1 = hv.y * p1.x + p1.y;
                float x2 = hv.z * p2.x + p2.y;
                float x3 = hv.w * p3.x + p3.y;
                v.x = (v.x + x0) * 0.5f;
                v.y = (v.y + x1) * 0.5f;
                v.z = (v.z + x2) * 0.5f;
                v.w = (v.w + x3) * 0.5f;
                ushort4 sp;
                sp.x = (v.x >= 1.0f) ? 0x3F80 : 0;
                sp.y = (v.y >= 1.0f) ? 0x3F80 : 0;
                sp.z = (v.z >= 1.0f) ? 0x3F80 : 0;
                sp.w = (v.w >= 1.0f) ? 0x3F80 : 0;
                v.x = (v.x >= 1.0f) ? 0.0f : v.x;
                v.y = (v.y >= 1.0f) ? 0.0f : v.y;
                v.z = (v.z >= 1.0f) ? 0.0f : v.z;
                v.w = (v.w >= 1.0f) ? 0.0f : v.w;
                unsigned row = (unsigned)(t4 * 16 + bn);
                unsigned off = (row * 512u + (unsigned)colq * 8u) ^ ((row & 7u) << 4);
                *(ushort4*)((char*)Asw + off) = sp;
            }
        }
    }
    __syncthreads();

    f32x4 acc[4][2] = {};

#pragma unroll
    for (int k0 = 0; k0 < 8; ++k0) {
        bf16x8 bb[6];
#pragma unroll
        for (int t_ = 0; t_ < 3; ++t_)
#pragma unroll
            for (int nf = 0; nf < 2; ++nf)
                bb[t_ * 2 + nf] = *(const bf16x8*)(Bbase + (size_t)t_ * 65536 +
                                                   nf * 4096 + k0 * 32);
#pragma unroll
        for (int half = 0; half < 2; ++half) {
            bf16x8 af[2];
#pragma unroll
            for (int m = 0; m < 2; ++m) {
                unsigned r = (unsigned)(32 * half + 16 * m + lrow);
                unsigned off = (r * 512u + (unsigned)(k0 * 64 + lchunk * 16)) ^ ((r & 7u) << 4);
                af[m] = *(const bf16x8*)((const char*)Asw + off);
            }
            __builtin_amdgcn_s_setprio(1);
#pragma unroll
            for (int t_ = 0; t_ < 3; ++t_)
#pragma unroll
                for (int nf = 0; nf < 2; ++nf)
#pragma unroll
                    for (int m = 0; m < 2; ++m) {
                        const int mf = half * 2 + m;
                        acc[mf][nf] = __builtin_amdgcn_mfma_f32_16x16x32_bf16(
                            af[m], bb[t_ * 2 + nf], acc[mf][nf], 0, 0, 0);
                    }
            __builtin_amdgcn_s_setprio(0);
        }
    }

    // ---- C write (local row L = 16*t4 + i -> G = t4*bnRows + bn0 + i) + stats -------
#pragma unroll
    for (int nf = 0; nf < 2; ++nf) {
        int col = 32 * wave + 16 * nf + lrow;
        float bvv = bias[col];
        double ss = 0.0, qq = 0.0;
#pragma unroll
        for (int mf = 0; mf < 4; ++mf) {
            int Lbase = 16 * mf + 4 * lchunk;
#pragma unroll
            for (int e = 0; e < 4; ++e) {
                int L = Lbase + e;
                size_t G = (size_t)(L >> 4) * bnRows + bn0 + (L & 15);
                float hv = acc[mf][nf][e] + bvv;
                C[G * 256 + col] = hv;
                ss += (double)hv;
                qq += (double)hv * (double)hv;
            }
        }
        ss += __shfl_xor(ss, 16);
        ss += __shfl_xor(ss, 32);
        qq += __shfl_xor(qq, 16);
        qq += __shfl_xor(qq, 32);
        if (lane < 16) {
            partial[(size_t)blk * 512 + col] = ss;
            partial[(size_t)blk * 512 + 256 + col] = qq;
        }
    }
}

// 256 blocks (one per channel) x 256 threads; fixed-order fp64 reduction.
__global__ __launch_bounds__(256) void finalize_stats(const double* __restrict__ partial,
                                                      const float* __restrict__ gamma,
                                                      const float* __restrict__ beta,
                                                      float2* __restrict__ ss,
                                                      int nblocks, double invM) {
    const int c = blockIdx.x;
    const int t = threadIdx.x;
    __shared__ double sh[256];
    __shared__ double sh2[256];
    double s = 0.0, s2 = 0.0;
    for (int b = t; b < nblocks; b += 256) {
        s += partial[(size_t)b * 512 + c];
        s2 += partial[(size_t)b * 512 + 256 + c];
    }
    sh[t] = s;
    sh2[t] = s2;
    __syncthreads();
#pragma unroll
    for (int off = 128; off > 0; off >>= 1) {
        if (t < off) {
            sh[t] += sh[t + off];
            sh2[t] += sh2[t + off];
        }
        __syncthreads();
    }
    if (t == 0) {
        double mu = sh[0] * invM;
        double var = sh2[0] * invM - mu * mu;
        double rstd = 1.0 / sqrt(var + 1e-5);
        double sc = (double)gamma[c] * rstd;
        ss[c] = make_float2((float)sc, (float)((double)beta[c] - mu * sc));
    }
}

__global__ __launch_bounds__(256) void bnlif_f32(const float* __restrict__ h,
                                                 const float2* __restrict__ ss,
                                                 float* __restrict__ out,
                                                 int slab4) {
    int t4 = blockIdx.x * 256 + threadIdx.x;
    if (t4 >= slab4) return;
    size_t idx = (size_t)t4 * 4;
    int c0 = (int)(idx & 255);
    float2 p0 = ss[c0], p1 = ss[c0 + 1], p2 = ss[c0 + 2], p3 = ss[c0 + 3];
    size_t slab = (size_t)slab4 * 4;
    float4 v = make_float4(0.f, 0.f, 0.f, 0.f);
#pragma unroll
    for (int t = 0; t < 4; ++t) {
        float4 hv = *(const float4*)(h + (size_t)t * slab + idx);
        float x0 = hv.x * p0.x + p0.y;
        float x1 = hv.y * p1.x + p1.y;
        float x2 = hv.z * p2.x + p2.y;
        float x3 = hv.w * p3.x + p3.y;
        v.x = (v.x + x0) * 0.5f;
        v.y = (v.y + x1) * 0.5f;
        v.z = (v.z + x2) * 0.5f;
        v.w = (v.w + x3) * 0.5f;
        float4 sp;
        sp.x = (v.x >= 1.0f) ? 1.0f : 0.0f;
        sp.y = (v.y >= 1.0f) ? 1.0f : 0.0f;
        sp.z = (v.z >= 1.0f) ? 1.0f : 0.0f;
        sp.w = (v.w >= 1.0f) ? 1.0f : 0.0f;
        v.x = (v.x >= 1.0f) ? 0.0f : v.x;
        v.y = (v.y >= 1.0f) ? 0.0f : v.y;
        v.z = (v.z >= 1.0f) ? 0.0f : v.z;
        v.w = (v.w >= 1.0f) ? 0.0f : v.w;
        *(float4*)(out + (size_t)t * slab + idx) = sp;
    }
}

extern "C" void kernel_launch(void* const* d_in, const int* in_sizes, int n_in,
                              void* d_out, int out_size, void* d_ws, size_t ws_size,
                              hipStream_t stream) {
    const float* x  = (const float*)d_in[0];
    const float* W1 = (const float*)d_in[1];
    const float* b1 = (const float*)d_in[2];
    const float* g1 = (const float*)d_in[3];
    const float* be1 = (const float*)d_in[4];
    const float* W2 = (const float*)d_in[5];
    const float* b2 = (const float*)d_in[6];
    const float* g2 = (const float*)d_in[7];
    const float* be2 = (const float*)d_in[8];
    float* out = (float*)d_out;

    const int M = in_sizes[0] / 256;            // 131072
    const int bnRows = M / 4;                   // 32768
    const size_t hBytes = (size_t)M * 256 * 4;  // 128 MiB

    char* ws = (char*)d_ws;
    float* h = (float*)ws;                                   // 128 MiB fp32 (h / o)
    double* partial = (double*)(ws + hBytes);                // 8 MiB ([block][512], NB=2048)
    unsigned short* W2catT = (unsigned short*)(ws + hBytes + (size_t)2048 * 512 * 8);
    float2* ss1 = (float2*)((char*)W2catT + 3 * 256 * 256 * 2);
    float2* ss2 = ss1 + 256;
    _Float16* W1hiT = (_Float16*)(ss2 + 256);
    _Float16* W1loT = W1hiT + 256 * 256;

    const int slab4 = M * 16;
    const double invM = 1.0 / (double)M;
    const int NB1 = M / 64;        // 2048
    const int NB2 = bnRows / 16;   // 2048

    dim3 blk(256);

    split_w1<<<dim3(256), blk, 0, stream>>>(W1, W1hiT, W1loT);
    split_w2<<<dim3(256), blk, 0, stream>>>(W2, W2catT);

    // ---- layer 1 (8 waves x 32 cols, 16 waves/CU + fused stats) ----
    gemm1_mfma<<<dim3(NB1), dim3(512), 0, stream>>>(x, W1hiT, W1loT, b1, h, partial);
    finalize_stats<<<dim3(256), blk, 0, stream>>>(partial, g1, be1, ss1, NB1, invM);

    // ---- layer 2 (BN+LIF fused staging; fused stats) ----
    gemm2_fused<<<dim3(NB2), dim3(512), 0, stream>>>(h, ss1, W2catT, b2, h, partial, bnRows);
    finalize_stats<<<dim3(256), blk, 0, stream>>>(partial, g2, be2, ss2, NB2, invM);
    bnlif_f32<<<dim3(slab4 / 256), blk, 0, stream>>>(h, ss2, out, slab4);
}